// Round 1
// baseline (8375.026 us; speedup 1.0000x reference)
//
#include <hip/hip_runtime.h>

#define HDIM 128

// ---------------- degree / normalization ----------------

__global__ __launch_bounds__(256) void k_init_deg(float* deg, int n) {
    int i = blockIdx.x * 256 + threadIdx.x;
    if (i < n) deg[i] = 1.0f;   // self-loop
}

__global__ __launch_bounds__(256) void k_count_deg(const int* __restrict__ dst,
                                                   float* deg, int e) {
    int i = blockIdx.x * 256 + threadIdx.x;
    if (i < e) unsafeAtomicAdd(&deg[dst[i]], 1.0f);
}

__global__ __launch_bounds__(256) void k_dinv(float* deg, int n) {
    int i = blockIdx.x * 256 + threadIdx.x;
    if (i < n) deg[i] = rsqrtf(deg[i]);   // deg >= 1 always
}

// ---------------- fused GEMM: g = dinv .* (A @ W); acc = g ----------------
// Tile: 128 rows x 128 cols per block, 256 threads, 8x8 outputs/thread.
// A may alias acc (in-place row update: all reads of a block's rows complete
// before its epilogue stores; separated by __syncthreads()).

template<int K>
__global__ __launch_bounds__(256) void k_gemm(const float* A,
                                              const float* __restrict__ W,
                                              const float* __restrict__ dinv,
                                              float* __restrict__ g,
                                              float* acc, int n)
{
    __shared__ float aT[32][132];   // [k][row], stride 132 (bank spread)
    __shared__ float wT[32][128];   // [k][col]

    const int tid  = threadIdx.x;
    const int colg = tid & 15;      // 16 groups x 8 cols
    const int rowg = tid >> 4;      // 16 groups x 8 rows
    const int row0 = blockIdx.x * 128;

    float accr[8][8];
    #pragma unroll
    for (int i = 0; i < 8; i++)
        #pragma unroll
        for (int j = 0; j < 8; j++) accr[i][j] = 0.0f;

    for (int k0 = 0; k0 < K; k0 += 32) {
        __syncthreads();
        // stage A tile: 128 rows x 32 k  (transposed into LDS)
        #pragma unroll
        for (int i = 0; i < 4; i++) {
            int idx = i * 256 + tid;       // 0..1023 float4 units
            int r   = idx >> 3;            // 0..127
            int kq  = idx & 7;             // 8 float4 per row
            float4 v = make_float4(0.f, 0.f, 0.f, 0.f);
            int grow = row0 + r;
            if (grow < n)
                v = *(const float4*)(A + (size_t)grow * K + k0 + kq * 4);
            aT[kq * 4 + 0][r] = v.x;
            aT[kq * 4 + 1][r] = v.y;
            aT[kq * 4 + 2][r] = v.z;
            aT[kq * 4 + 3][r] = v.w;
        }
        // stage W tile: 32 k x 128 cols
        #pragma unroll
        for (int i = 0; i < 4; i++) {
            int idx = i * 256 + tid;       // 0..1023 float4 units
            int kr  = idx >> 5;            // 0..31
            int cq  = idx & 31;            // 32 float4 per k-row
            *(float4*)&wT[kr][cq * 4] =
                *(const float4*)(W + (size_t)(k0 + kr) * HDIM + cq * 4);
        }
        __syncthreads();

        #pragma unroll 8
        for (int kk = 0; kk < 32; kk++) {
            float4 a0 = *(const float4*)&aT[kk][rowg * 8];
            float4 a1 = *(const float4*)&aT[kk][rowg * 8 + 4];
            float4 w0 = *(const float4*)&wT[kk][colg * 8];
            float4 w1 = *(const float4*)&wT[kk][colg * 8 + 4];
            float av[8] = {a0.x, a0.y, a0.z, a0.w, a1.x, a1.y, a1.z, a1.w};
            float wv[8] = {w0.x, w0.y, w0.z, w0.w, w1.x, w1.y, w1.z, w1.w};
            #pragma unroll
            for (int i = 0; i < 8; i++)
                #pragma unroll
                for (int j = 0; j < 8; j++)
                    accr[i][j] = fmaf(av[i], wv[j], accr[i][j]);
        }
    }

    // epilogue: scale by dinv[row]; write g and acc (= self-loop init)
    #pragma unroll
    for (int i = 0; i < 8; i++) {
        int row = row0 + rowg * 8 + i;
        if (row < n) {
            float di = dinv[row];
            size_t base = (size_t)row * HDIM + colg * 8;
            float4 o0, o1;
            o0.x = accr[i][0] * di; o0.y = accr[i][1] * di;
            o0.z = accr[i][2] * di; o0.w = accr[i][3] * di;
            o1.x = accr[i][4] * di; o1.y = accr[i][5] * di;
            o1.z = accr[i][6] * di; o1.w = accr[i][7] * di;
            *(float4*)(g + base)       = o0;
            *(float4*)(g + base + 4)   = o1;
            *(float4*)(acc + base)     = o0;
            *(float4*)(acc + base + 4) = o1;
        }
    }
}

// ---------------- edge scatter-add: acc[dst] += g[src] ----------------
// 32 threads per edge, float4 per thread (128 floats/row).

__global__ __launch_bounds__(256) void k_scatter(const float* __restrict__ g,
                                                 float* __restrict__ acc,
                                                 const int* __restrict__ src,
                                                 const int* __restrict__ dst,
                                                 int e)
{
    int t  = blockIdx.x * 256 + threadIdx.x;
    int ed = t >> 5;
    int l  = t & 31;
    if (ed < e) {
        int s = src[ed], d = dst[ed];
        float4 v = *(const float4*)(g + (size_t)s * HDIM + l * 4);
        float* o = acc + (size_t)d * HDIM + l * 4;
        unsafeAtomicAdd(o + 0, v.x);
        unsafeAtomicAdd(o + 1, v.y);
        unsafeAtomicAdd(o + 2, v.z);
        unsafeAtomicAdd(o + 3, v.w);
    }
}

// ---------------- epilogue: act = [relu](dinv*acc + b), in place ----------------

template<bool RELU>
__global__ __launch_bounds__(256) void k_finish(float* acc,
                                                const float* __restrict__ dinv,
                                                const float* __restrict__ bias,
                                                int n)
{
    int t   = blockIdx.x * 256 + threadIdx.x;
    int row = t >> 5;
    int l   = t & 31;
    if (row < n) {
        float di = dinv[row];
        float4 bb = *(const float4*)(bias + l * 4);
        float4 v  = *(float4*)(acc + (size_t)row * HDIM + l * 4);
        v.x = fmaf(di, v.x, bb.x);
        v.y = fmaf(di, v.y, bb.y);
        v.z = fmaf(di, v.z, bb.z);
        v.w = fmaf(di, v.w, bb.w);
        if (RELU) {
            v.x = fmaxf(v.x, 0.f); v.y = fmaxf(v.y, 0.f);
            v.z = fmaxf(v.z, 0.f); v.w = fmaxf(v.w, 0.f);
        }
        *(float4*)(acc + (size_t)row * HDIM + l * 4) = v;
    }
}

// ---------------- launch ----------------

extern "C" void kernel_launch(void* const* d_in, const int* in_sizes, int n_in,
                              void* d_out, int out_size, void* d_ws, size_t ws_size,
                              hipStream_t stream)
{
    const float* x  = (const float*)d_in[0];
    const int*   ei = (const int*)d_in[1];
    const float* W1 = (const float*)d_in[2];
    const float* b1 = (const float*)d_in[3];
    const float* W2 = (const float*)d_in[4];
    const float* b2 = (const float*)d_in[5];
    const float* W3 = (const float*)d_in[6];
    const float* b3 = (const float*)d_in[7];
    float* out = (float*)d_out;

    const int n = in_sizes[0] / 256;   // IN = 256
    const int E = in_sizes[1] / 2;
    const int* src = ei;
    const int* dst = ei + E;

    // workspace: dinv (N floats) @0, g buffer (N*128 floats) @1MB
    char*  ws   = (char*)d_ws;
    float* dinv = (float*)ws;
    float* g    = (float*)(ws + (1 << 20));

    dim3 blk(256);
    int ngrid = (n + 255) / 256;
    int egrid = (E + 255) / 256;

    k_init_deg<<<ngrid, blk, 0, stream>>>(dinv, n);
    k_count_deg<<<egrid, blk, 0, stream>>>(dst, dinv, E);
    k_dinv<<<ngrid, blk, 0, stream>>>(dinv, n);

    int gemm_grid = (n + 127) / 128;
    int scat_grid = (int)(((size_t)E * 32 + 255) / 256);
    int fin_grid  = (int)(((size_t)n * 32 + 255) / 256);

    // layer 1: in = x (K=256), act buffer = d_out
    k_gemm<256><<<gemm_grid, blk, 0, stream>>>(x, W1, dinv, g, out, n);
    k_scatter<<<scat_grid, blk, 0, stream>>>(g, out, src, dst, E);
    k_finish<true><<<fin_grid, blk, 0, stream>>>(out, dinv, b1, n);

    // layer 2: in-place on d_out (K=128)
    k_gemm<128><<<gemm_grid, blk, 0, stream>>>(out, W2, dinv, g, out, n);
    k_scatter<<<scat_grid, blk, 0, stream>>>(g, out, src, dst, E);
    k_finish<true><<<fin_grid, blk, 0, stream>>>(out, dinv, b2, n);

    // layer 3: in-place on d_out (K=128), no relu
    k_gemm<128><<<gemm_grid, blk, 0, stream>>>(out, W3, dinv, g, out, n);
    k_scatter<<<scat_grid, blk, 0, stream>>>(g, out, src, dst, E);
    k_finish<false><<<fin_grid, blk, 0, stream>>>(out, dinv, b3, n);
}

// Round 2
// 734.175 us; speedup vs baseline: 11.4074x; 11.4074x over previous
//
#include <hip/hip_runtime.h>

#define HDIM 128

// ======================= CSR build =======================

__global__ __launch_bounds__(256) void k_count(const int* __restrict__ dst,
                                               int* __restrict__ cnt, int e) {
    int i = blockIdx.x * 256 + threadIdx.x;
    if (i < e) atomicAdd(&cnt[dst[i]], 1);
}

__global__ __launch_bounds__(256) void k_dinv(const int* __restrict__ cnt,
                                              float* __restrict__ dinv, int n) {
    int i = blockIdx.x * 256 + threadIdx.x;
    if (i < n) dinv[i] = rsqrtf((float)(cnt[i] + 1));   // +1 self-loop
}

// block-wise exclusive scan (256/block) + block sums
__global__ __launch_bounds__(256) void k_scan1(const int* __restrict__ cnt,
                                               int* __restrict__ offs,
                                               int* __restrict__ bsum, int n) {
    __shared__ int sm[256];
    int tid = threadIdx.x;
    int i = blockIdx.x * 256 + tid;
    int v = (i < n) ? cnt[i] : 0;
    sm[tid] = v;
    __syncthreads();
    for (int off = 1; off < 256; off <<= 1) {
        int t = (tid >= off) ? sm[tid - off] : 0;
        __syncthreads();
        sm[tid] += t;
        __syncthreads();
    }
    if (i < n) offs[i] = sm[tid] - v;            // exclusive
    if (tid == 255) bsum[blockIdx.x] = sm[255];  // block total
}

// single-block exclusive scan of block sums (nb <= 512)
__global__ __launch_bounds__(512) void k_scan2(int* __restrict__ bsum, int nb) {
    __shared__ int sm[512];
    int tid = threadIdx.x;
    int v = (tid < nb) ? bsum[tid] : 0;
    sm[tid] = v;
    __syncthreads();
    for (int off = 1; off < 512; off <<= 1) {
        int t = (tid >= off) ? sm[tid - off] : 0;
        __syncthreads();
        sm[tid] += t;
        __syncthreads();
    }
    if (tid < nb) bsum[tid] = sm[tid] - v;       // exclusive
}

__global__ __launch_bounds__(256) void k_scan3(int* __restrict__ offs,
                                               const int* __restrict__ bsum,
                                               int n, int e) {
    int i = blockIdx.x * 256 + threadIdx.x;
    if (i < n) offs[i] += bsum[blockIdx.x];
    if (i == 0) offs[n] = e;
}

__global__ __launch_bounds__(256) void k_fill(const int* __restrict__ src,
                                              const int* __restrict__ dst,
                                              const int* __restrict__ offs,
                                              int* __restrict__ cursor,
                                              int* __restrict__ csr, int e) {
    int i = blockIdx.x * 256 + threadIdx.x;
    if (i < e) {
        int d = dst[i];
        int p = offs[d] + atomicAdd(&cursor[d], 1);
        csr[p] = src[i];
    }
}

// =============== fused GEMM: g = dinv .* (A @ W) ===============
// 128x128 tile, 256 threads, 8x8 outputs/thread. A may alias d_out safely
// (A only read here; g is a separate buffer).

template<int K>
__global__ __launch_bounds__(256) void k_gemm(const float* __restrict__ A,
                                              const float* __restrict__ W,
                                              const float* __restrict__ dinv,
                                              float* __restrict__ g, int n)
{
    __shared__ float aT[32][132];
    __shared__ float wT[32][128];

    const int tid  = threadIdx.x;
    const int colg = tid & 15;
    const int rowg = tid >> 4;
    const int row0 = blockIdx.x * 128;

    float accr[8][8];
    #pragma unroll
    for (int i = 0; i < 8; i++)
        #pragma unroll
        for (int j = 0; j < 8; j++) accr[i][j] = 0.0f;

    for (int k0 = 0; k0 < K; k0 += 32) {
        __syncthreads();
        #pragma unroll
        for (int i = 0; i < 4; i++) {
            int idx = i * 256 + tid;
            int r   = idx >> 3;
            int kq  = idx & 7;
            float4 v = make_float4(0.f, 0.f, 0.f, 0.f);
            int grow = row0 + r;
            if (grow < n)
                v = *(const float4*)(A + (size_t)grow * K + k0 + kq * 4);
            aT[kq * 4 + 0][r] = v.x;
            aT[kq * 4 + 1][r] = v.y;
            aT[kq * 4 + 2][r] = v.z;
            aT[kq * 4 + 3][r] = v.w;
        }
        #pragma unroll
        for (int i = 0; i < 4; i++) {
            int idx = i * 256 + tid;
            int kr  = idx >> 5;
            int cq  = idx & 31;
            *(float4*)&wT[kr][cq * 4] =
                *(const float4*)(W + (size_t)(k0 + kr) * HDIM + cq * 4);
        }
        __syncthreads();

        #pragma unroll 8
        for (int kk = 0; kk < 32; kk++) {
            float4 a0 = *(const float4*)&aT[kk][rowg * 8];
            float4 a1 = *(const float4*)&aT[kk][rowg * 8 + 4];
            float4 w0 = *(const float4*)&wT[kk][colg * 8];
            float4 w1 = *(const float4*)&wT[kk][colg * 8 + 4];
            float av[8] = {a0.x, a0.y, a0.z, a0.w, a1.x, a1.y, a1.z, a1.w};
            float wv[8] = {w0.x, w0.y, w0.z, w0.w, w1.x, w1.y, w1.z, w1.w};
            #pragma unroll
            for (int i = 0; i < 8; i++)
                #pragma unroll
                for (int j = 0; j < 8; j++)
                    accr[i][j] = fmaf(av[i], wv[j], accr[i][j]);
        }
    }

    #pragma unroll
    for (int i = 0; i < 8; i++) {
        int row = row0 + rowg * 8 + i;
        if (row < n) {
            float di = dinv[row];
            size_t base = (size_t)row * HDIM + colg * 8;
            float4 o0, o1;
            o0.x = accr[i][0] * di; o0.y = accr[i][1] * di;
            o0.z = accr[i][2] * di; o0.w = accr[i][3] * di;
            o1.x = accr[i][4] * di; o1.y = accr[i][5] * di;
            o1.z = accr[i][6] * di; o1.w = accr[i][7] * di;
            *(float4*)(g + base)     = o0;
            *(float4*)(g + base + 4) = o1;
        }
    }
}

// =============== gather + finish: out = [relu](dinv*(g[d] + sum g[src]) + b) ===============
// 32 threads per node, float4 per thread.

template<bool RELU>
__global__ __launch_bounds__(256) void k_gather(const float* __restrict__ g,
                                                const int* __restrict__ csr,
                                                const int* __restrict__ offs,
                                                const float* __restrict__ dinv,
                                                const float* __restrict__ bias,
                                                float* __restrict__ out, int n)
{
    int t    = blockIdx.x * 256 + threadIdx.x;
    int node = t >> 5;
    int l    = t & 31;
    if (node >= n) return;

    int e0 = offs[node];
    int e1 = offs[node + 1];

    // self-loop term
    float4 acc = *(const float4*)(g + (size_t)node * HDIM + l * 4);

    int e = e0;
    for (; e + 1 < e1; e += 2) {           // 2-deep for load overlap
        int s0 = csr[e];
        int s1 = csr[e + 1];
        float4 v0 = *(const float4*)(g + (size_t)s0 * HDIM + l * 4);
        float4 v1 = *(const float4*)(g + (size_t)s1 * HDIM + l * 4);
        acc.x += v0.x; acc.y += v0.y; acc.z += v0.z; acc.w += v0.w;
        acc.x += v1.x; acc.y += v1.y; acc.z += v1.z; acc.w += v1.w;
    }
    if (e < e1) {
        int s = csr[e];
        float4 v = *(const float4*)(g + (size_t)s * HDIM + l * 4);
        acc.x += v.x; acc.y += v.y; acc.z += v.z; acc.w += v.w;
    }

    float di  = dinv[node];
    float4 bb = *(const float4*)(bias + l * 4);
    float4 o;
    o.x = fmaf(di, acc.x, bb.x);
    o.y = fmaf(di, acc.y, bb.y);
    o.z = fmaf(di, acc.z, bb.z);
    o.w = fmaf(di, acc.w, bb.w);
    if (RELU) {
        o.x = fmaxf(o.x, 0.f); o.y = fmaxf(o.y, 0.f);
        o.z = fmaxf(o.z, 0.f); o.w = fmaxf(o.w, 0.f);
    }
    *(float4*)(out + (size_t)node * HDIM + l * 4) = o;
}

// ======================= launch =======================

extern "C" void kernel_launch(void* const* d_in, const int* in_sizes, int n_in,
                              void* d_out, int out_size, void* d_ws, size_t ws_size,
                              hipStream_t stream)
{
    const float* x  = (const float*)d_in[0];
    const int*   ei = (const int*)d_in[1];
    const float* W1 = (const float*)d_in[2];
    const float* b1 = (const float*)d_in[3];
    const float* W2 = (const float*)d_in[4];
    const float* b2 = (const float*)d_in[5];
    const float* W3 = (const float*)d_in[6];
    const float* b3 = (const float*)d_in[7];
    float* out = (float*)d_out;

    const int n = in_sizes[0] / 256;   // IN = 256
    const int E = in_sizes[1] / 2;
    const int* src = ei;
    const int* dst = ei + E;

    // workspace layout (bytes):
    //   dinv   @ 0        (n*4      ~400KB)
    //   cnt    @ 512K     (n*4, also reused as fill cursor)
    //   offs   @ 1M       ((n+1)*4)
    //   bsum   @ 1536K    (~2KB)
    //   csr    @ 1600K    (E*4 = 6.4MB)
    //   g      @ 8M       (n*128*4 = 51.2MB)
    char*  ws   = (char*)d_ws;
    float* dinv = (float*)(ws);
    int*   cnt  = (int*)(ws + (512 << 10));
    int*   offs = (int*)(ws + (1 << 20));
    int*   bsum = (int*)(ws + (1536 << 10));
    int*   csr  = (int*)(ws + (1600 << 10));
    float* g    = (float*)(ws + (8 << 20));

    dim3 blk(256);
    int ngrid = (n + 255) / 256;            // 391
    int egrid = (E + 255) / 256;            // 6250

    // ---- CSR build + norms ----
    hipMemsetAsync(cnt, 0, (size_t)n * 4, stream);
    k_count<<<egrid, blk, 0, stream>>>(dst, cnt, E);
    k_dinv<<<ngrid, blk, 0, stream>>>(cnt, dinv, n);
    k_scan1<<<ngrid, blk, 0, stream>>>(cnt, offs, bsum, n);
    k_scan2<<<1, 512, 0, stream>>>(bsum, ngrid);
    k_scan3<<<ngrid, blk, 0, stream>>>(offs, bsum, n, E);
    hipMemsetAsync(cnt, 0, (size_t)n * 4, stream);   // reuse as cursor
    k_fill<<<egrid, blk, 0, stream>>>(src, dst, offs, cnt, csr, E);

    int gemm_grid = (n + 127) / 128;
    int gat_grid  = (int)(((size_t)n * 32 + 255) / 256);

    // layer 1 (K=256)
    k_gemm<256><<<gemm_grid, blk, 0, stream>>>(x, W1, dinv, g, n);
    k_gather<true><<<gat_grid, blk, 0, stream>>>(g, csr, offs, dinv, b1, out, n);
    // layer 2 (K=128)
    k_gemm<128><<<gemm_grid, blk, 0, stream>>>(out, W2, dinv, g, n);
    k_gather<true><<<gat_grid, blk, 0, stream>>>(g, csr, offs, dinv, b2, out, n);
    // layer 3 (K=128)
    k_gemm<128><<<gemm_grid, blk, 0, stream>>>(out, W3, dinv, g, n);
    k_gather<false><<<gat_grid, blk, 0, stream>>>(g, csr, offs, dinv, b3, out, n);
}